// Round 16
// baseline (131.094 us; speedup 1.0000x reference)
//
#include <hip/hip_runtime.h>
#include <hip/hip_bf16.h>

#define T_ 8
#define H_ 96
#define W_ 160
#define C_ 256
#define F_ 256
#define M_ (T_ * H_ * W_)   // 122880

typedef __bf16 bf16_t;
typedef __bf16 bf16x2 __attribute__((ext_vector_type(2)));
typedef __bf16 bf16x8 __attribute__((ext_vector_type(8)));
typedef float  f32x2  __attribute__((ext_vector_type(2)));
typedef float  f32x4  __attribute__((ext_vector_type(4)));

// ---------------- pass 0: WpT[f][c] = bf16(Wp[c][f]) ----------------
__global__ void wp_transpose_kernel(const float* __restrict__ Wp,
                                    bf16_t* __restrict__ WpT) {
    int c = blockIdx.x;   // 0..255
    int f = threadIdx.x;  // 0..255
    WpT[f * C_ + c] = (bf16_t)Wp[c * F_ + f];
}

// ---------------- pass 1: depthwise 3x3x3, rolling h-strip + w-pair ---------
// Byte-law (fits r1..r15 within ~10%): dur = requested_vmem / ~6.9 MB/us.
// r15 amp = 3(w) x 10/8(h) = 3.75 -> 472MB -> 77us. This round: thread owns a
// w-PAIR; per plane 4 w-cols serve both outputs -> amp 2.5 -> 315MB.
// Register discipline (r5/r14 lesson): weights live in LDS (not regs);
// live set = acc 96 + v 64 + 18 transient wv + addr ~15 = ~190 < 256 cap.
#define PLANE(I)                                                              \
  {                                                                           \
    const int hh = h0 + (I) - 1;                                              \
    f32x2 v[4][8];                                                            \
    _Pragma("unroll") for (int j = 0; j < 4; ++j)                             \
      _Pragma("unroll") for (int tt = 0; tt < 8; ++tt) v[j][tt] = f32x2{};    \
    if (hh >= 0 && hh < H_) {            /* block-uniform */                  \
      const float* pb = x + (((long)hh * W_ + w0) * C_ + c);                  \
      _Pragma("unroll") for (int tt = 0; tt < 8; ++tt)                        \
        v[1][tt] = *(const f32x2*)(pb + (long)tt * tstride);                  \
      _Pragma("unroll") for (int tt = 0; tt < 8; ++tt)                        \
        v[2][tt] = *(const f32x2*)(pb + C_ + (long)tt * tstride);             \
      if (hasL) {                                                             \
        _Pragma("unroll") for (int tt = 0; tt < 8; ++tt)                      \
          v[0][tt] = *(const f32x2*)(pb - C_ + (long)tt * tstride);           \
      }                                                                       \
      if (hasR) {                                                             \
        _Pragma("unroll") for (int tt = 0; tt < 8; ++tt)                      \
          v[3][tt] = *(const f32x2*)(pb + 2 * C_ + (long)tt * tstride);       \
      }                                                                       \
    }                                                                         \
    _Pragma("unroll") for (int kh = 0; kh < 3; ++kh) {                        \
      const int ko = (I) - kh;           /* literal after unroll */           \
      if (ko >= 0 && ko <= 7) {                                               \
        f32x2 wv[9];                                                          \
        _Pragma("unroll") for (int kt = 0; kt < 3; ++kt)                      \
          _Pragma("unroll") for (int kw = 0; kw < 3; ++kw)                    \
            wv[kt * 3 + kw] =                                                 \
                *(const f32x2*)&Ws[((kt * 3 + kh) * 3 + kw) * C_ + c];        \
        _Pragma("unroll") for (int to = 0; to < 8; ++to) {                    \
          f32x2 s0 = f32x2{}, s1 = f32x2{};                                   \
          _Pragma("unroll") for (int kt = 0; kt < 3; ++kt) {                  \
            const int ti = to + kt - 1;                                       \
            if (ti >= 0 && ti < 8) {                                          \
              _Pragma("unroll") for (int kw = 0; kw < 3; ++kw) {              \
                s0 += v[kw][ti] * wv[kt * 3 + kw];                            \
                s1 += v[kw + 1][ti] * wv[kt * 3 + kw];                        \
              }                                                               \
            }                                                                 \
          }                                                                   \
          if (kh == 0) { acc[ko][to][0] = s0; acc[ko][to][1] = s1; }          \
          else         { acc[ko][to][0] += s0; acc[ko][to][1] += s1; }        \
        }                                                                     \
      }                                                                       \
    }                                                                         \
    const int kd = (I) - 2;                                                   \
    if (kd >= 0 && kd <= 7) {                                                 \
      _Pragma("unroll") for (int tt = 0; tt < 8; ++tt) {                      \
        bf16x2 o0, o1;                                                        \
        o0[0] = (bf16_t)acc[kd][tt][0][0];                                    \
        o0[1] = (bf16_t)acc[kd][tt][0][1];                                    \
        o1[0] = (bf16_t)acc[kd][tt][1][0];                                    \
        o1[1] = (bf16_t)acc[kd][tt][1][1];                                    \
        bf16_t* pd = &dw[(((long)tt * H_ + h0 + kd) * W_ + w0) * C_ + c];     \
        *(bf16x2*)pd = o0;                                                    \
        *(bf16x2*)(pd + C_) = o1;                                             \
      }                                                                       \
    }                                                                         \
  }

__global__ __launch_bounds__(128, 2) void dw_conv_kernel(const float* __restrict__ x,
                                                         const float* __restrict__ Wd,
                                                         bf16_t* __restrict__ dw) {
    __shared__ float Ws[27 * C_];     // 27648 B

    for (int i = threadIdx.x; i < 27 * 64; i += 128) {
        int k = i >> 6, q = i & 63;
        *(f32x4*)&Ws[k * C_ + q * 4] = *(const f32x4*)&Wd[k * C_ + q * 4];
    }
    __syncthreads();

    // XCD-chunked swizzle: grid 960 % 8 == 0 -> bijective
    int nchunk = gridDim.x >> 3;
    int bb  = (blockIdx.x & 7) * nchunk + (blockIdx.x >> 3);
    int hs  = bb / (W_ / 2);         // strip, 0..11
    int wp  = bb % (W_ / 2);         // w-pair, 0..79 (adjacent bb share halos)
    int h0  = hs * 8;
    int w0  = wp * 2;                // outputs {w0, w0+1}
    int tid = threadIdx.x;           // 0..127
    int c   = tid * 2;               // channel pair

    const bool hasL = (w0 > 0);          // block-uniform
    const bool hasR = (w0 + 2 < W_);     // block-uniform
    const int tstride = H_ * W_ * C_;

    f32x2 acc[8][8][2];              // [h-out][t][iw]; live window <= 3 h-sets

    PLANE(0) PLANE(1) PLANE(2) PLANE(3) PLANE(4)
    PLANE(5) PLANE(6) PLANE(7) PLANE(8) PLANE(9)
}

// ---------------- pass 2: GEMM [M,256]x[256,256] bf16 MFMA + ReLU ----------------
#define BM 128
#define BN 128
#define BK 32
#define LDSTR 40  // 32 + 8 pad: fragment ds_read_b128 2-way (free) instead of 8-way

__global__ __launch_bounds__(256) void gemm_kernel(const bf16_t* __restrict__ A,   // dw  [M][C]
                                                   const bf16_t* __restrict__ Bt,  // WpT [F][C] (n-major)
                                                   float* __restrict__ out) {      // [M][F]
    __shared__ __align__(16) bf16_t As[BM * LDSTR];
    __shared__ __align__(16) bf16_t Bs[BN * LDSTR];

    int m0   = blockIdx.x * BM;
    int n0   = blockIdx.y * BN;
    int tid  = threadIdx.x;
    int lane = tid & 63;
    int wid  = tid >> 6;
    int wr   = wid >> 1;   // 0..1
    int wc   = wid & 1;    // 0..1
    int r16  = lane & 15;
    int kg   = lane >> 4;  // 0..3

    f32x4 acc[4][4] = {};

    for (int k0 = 0; k0 < C_; k0 += BK) {
        __syncthreads();
#pragma unroll
        for (int it = 0; it < 2; ++it) {
            int slot = tid + it * 256;       // 0..511
            int row  = slot >> 2;            // 0..127
            int seg  = slot & 3;             // 0..3 (8 bf16 each)
            uint4 va = *(const uint4*)&A[(long)(m0 + row) * C_ + k0 + seg * 8];
            *(uint4*)&As[row * LDSTR + seg * 8] = va;
            uint4 vb = *(const uint4*)&Bt[(n0 + row) * C_ + k0 + seg * 8];
            *(uint4*)&Bs[row * LDSTR + seg * 8] = vb;
        }
        __syncthreads();

        bf16x8 af[4], bfr[4];
#pragma unroll
        for (int m = 0; m < 4; ++m)
            af[m] = *(const bf16x8*)&As[(wr * 64 + m * 16 + r16) * LDSTR + kg * 8];
#pragma unroll
        for (int n = 0; n < 4; ++n)
            bfr[n] = *(const bf16x8*)&Bs[(wc * 64 + n * 16 + r16) * LDSTR + kg * 8];

#pragma unroll
        for (int m = 0; m < 4; ++m)
#pragma unroll
            for (int n = 0; n < 4; ++n)
                acc[m][n] = __builtin_amdgcn_mfma_f32_16x16x32_bf16(af[m], bfr[n], acc[m][n], 0, 0, 0);
    }

    // epilogue: ReLU + fp32 store.  D layout: row=(l>>4)*4+r, col=l&15
    int rbase = m0 + wr * 64 + kg * 4;
    int cbase = n0 + wc * 64 + r16;
#pragma unroll
    for (int m = 0; m < 4; ++m)
#pragma unroll
        for (int n = 0; n < 4; ++n)
#pragma unroll
            for (int r = 0; r < 4; ++r) {
                float v = acc[m][n][r];
                v = v > 0.f ? v : 0.f;
                out[(long)(rbase + m * 16 + r) * F_ + cbase + n * 16] = v;
            }
}

extern "C" void kernel_launch(void* const* d_in, const int* in_sizes, int n_in,
                              void* d_out, int out_size, void* d_ws, size_t ws_size,
                              hipStream_t stream) {
    const float* x  = (const float*)d_in[0];
    const float* Wd = (const float*)d_in[1];
    const float* Wp = (const float*)d_in[2];
    float* out = (float*)d_out;

    bf16_t* dw  = (bf16_t*)d_ws;                                  // M_*C_ bf16 = 62,914,560 B
    bf16_t* WpT = (bf16_t*)((char*)d_ws + (size_t)M_ * C_ * 2);   // + 131,072 B

    wp_transpose_kernel<<<C_, F_, 0, stream>>>(Wp, WpT);
    dw_conv_kernel<<<(H_ / 8) * (W_ / 2), 128, 0, stream>>>(x, Wd, dw);
    gemm_kernel<<<dim3(M_ / BM, F_ / BN), 256, 0, stream>>>(dw, WpT, out);
}

// Round 17
// 104.747 us; speedup vs baseline: 1.2515x; 1.2515x over previous
//
#include <hip/hip_runtime.h>
#include <hip/hip_bf16.h>

#define T_ 8
#define H_ 96
#define W_ 160
#define C_ 256
#define F_ 256
#define M_ (T_ * H_ * W_)   // 122880

typedef __bf16 bf16_t;
typedef __bf16 bf16x8 __attribute__((ext_vector_type(8)));
typedef float  f32x4  __attribute__((ext_vector_type(4)));

// ---------------- pass 0: WpT[f][c] = bf16(Wp[c][f]) ----------------
__global__ void wp_transpose_kernel(const float* __restrict__ Wp,
                                    bf16_t* __restrict__ WpT) {
    int c = blockIdx.x;   // 0..255
    int f = threadIdx.x;  // 0..255
    WpT[f * C_ + c] = (bf16_t)Wp[c * F_ + f];
}

// ---------------- pass 1: depthwise 3x3x3, rolling h-strip + w-pair, scalar ---
// Byte-law: dur = requested_vmem / ~6.6-6.9 MB/us. r15 (amp 3.75, 472MB) = 77us.
// This round: w-pair reuse at SCALAR width so the live set fits the compiler's
// hard 128-VGPR target (r16 lesson: it spills rather than exceed 128).
// Live set: v 32 + acc-window 48 + wreg 27 + addr ~15 = ~122 <= 128.
// Requested: 10 planes x 32 loads x 4B -> amp 2.5 = 315MB (+61 stores).
#define PLANE(I)                                                              \
  {                                                                           \
    const int hh = h0 + (I) - 1;                                              \
    float v[4][8];                                                            \
    _Pragma("unroll") for (int j = 0; j < 4; ++j)                             \
      _Pragma("unroll") for (int tt = 0; tt < 8; ++tt) v[j][tt] = 0.f;        \
    if (hh >= 0 && hh < H_) {            /* block-uniform */                  \
      const float* pb = x + (((long)hh * W_ + w0) * C_ + c);                  \
      _Pragma("unroll") for (int tt = 0; tt < 8; ++tt)                        \
        v[1][tt] = pb[(long)tt * tstride];                                    \
      _Pragma("unroll") for (int tt = 0; tt < 8; ++tt)                        \
        v[2][tt] = pb[C_ + (long)tt * tstride];                               \
      if (hasL) {                                                             \
        _Pragma("unroll") for (int tt = 0; tt < 8; ++tt)                      \
          v[0][tt] = pb[-C_ + (long)tt * tstride];                            \
      }                                                                       \
      if (hasR) {                                                             \
        _Pragma("unroll") for (int tt = 0; tt < 8; ++tt)                      \
          v[3][tt] = pb[2 * C_ + (long)tt * tstride];                         \
      }                                                                       \
    }                                                                         \
    _Pragma("unroll") for (int kh = 0; kh < 3; ++kh) {                        \
      const int ko = (I) - kh;           /* literal after unroll */           \
      if (ko >= 0 && ko <= 7) {                                               \
        _Pragma("unroll") for (int to = 0; to < 8; ++to) {                    \
          float s0 = 0.f, s1 = 0.f;                                           \
          _Pragma("unroll") for (int kt = 0; kt < 3; ++kt) {                  \
            const int ti = to + kt - 1;                                       \
            if (ti >= 0 && ti < 8) {                                          \
              _Pragma("unroll") for (int kw = 0; kw < 3; ++kw) {              \
                const float wv = wreg[(kt * 3 + kh) * 3 + kw];                \
                s0 += v[kw][ti] * wv;                                         \
                s1 += v[kw + 1][ti] * wv;                                     \
              }                                                               \
            }                                                                 \
          }                                                                   \
          if (kh == 0) { acc[ko][to][0] = s0;  acc[ko][to][1] = s1; }         \
          else         { acc[ko][to][0] += s0; acc[ko][to][1] += s1; }        \
        }                                                                     \
      }                                                                       \
    }                                                                         \
    const int kd = (I) - 2;                                                   \
    if (kd >= 0 && kd <= 7) {                                                 \
      _Pragma("unroll") for (int tt = 0; tt < 8; ++tt) {                      \
        bf16_t* pd = &dw[(((long)tt * H_ + h0 + kd) * W_ + w0) * C_ + c];     \
        pd[0]  = (bf16_t)acc[kd][tt][0];                                      \
        pd[C_] = (bf16_t)acc[kd][tt][1];                                      \
      }                                                                       \
    }                                                                         \
  }

__global__ __launch_bounds__(256, 2) void dw_conv_kernel(const float* __restrict__ x,
                                                         const float* __restrict__ Wd,
                                                         bf16_t* __restrict__ dw) {
    // XCD-chunked swizzle: grid 960 % 8 == 0 -> bijective
    int nchunk = gridDim.x >> 3;
    int bb  = (blockIdx.x & 7) * nchunk + (blockIdx.x >> 3);
    int hs  = bb / (W_ / 2);         // strip, 0..11
    int wp  = bb % (W_ / 2);         // w-pair, 0..79 (adjacent bb share halos)
    int h0  = hs * 8;
    int w0  = wp * 2;                // outputs {w0, w0+1}
    int tid = threadIdx.x;           // 0..255
    int c   = tid;                   // one channel per thread

    const bool hasL = (w0 > 0);          // block-uniform
    const bool hasR = (w0 + 2 < W_);     // block-uniform
    const int tstride = H_ * W_ * C_;

    float wreg[27];
#pragma unroll
    for (int k = 0; k < 27; ++k) wreg[k] = Wd[k * C_ + c];

    float acc[8][8][2];              // [h-out][t][iw]; live window <= 3 h-sets

    PLANE(0) PLANE(1) PLANE(2) PLANE(3) PLANE(4)
    PLANE(5) PLANE(6) PLANE(7) PLANE(8) PLANE(9)
}

// ---------------- pass 2: GEMM [M,256]x[256,256] bf16 MFMA + ReLU ----------------
#define BM 128
#define BN 128
#define BK 32
#define LDSTR 40  // 32 + 8 pad: fragment ds_read_b128 2-way (free) instead of 8-way

__global__ __launch_bounds__(256) void gemm_kernel(const bf16_t* __restrict__ A,   // dw  [M][C]
                                                   const bf16_t* __restrict__ Bt,  // WpT [F][C] (n-major)
                                                   float* __restrict__ out) {      // [M][F]
    __shared__ __align__(16) bf16_t As[BM * LDSTR];
    __shared__ __align__(16) bf16_t Bs[BN * LDSTR];

    int m0   = blockIdx.x * BM;
    int n0   = blockIdx.y * BN;
    int tid  = threadIdx.x;
    int lane = tid & 63;
    int wid  = tid >> 6;
    int wr   = wid >> 1;   // 0..1
    int wc   = wid & 1;    // 0..1
    int r16  = lane & 15;
    int kg   = lane >> 4;  // 0..3

    f32x4 acc[4][4] = {};

    for (int k0 = 0; k0 < C_; k0 += BK) {
        __syncthreads();
#pragma unroll
        for (int it = 0; it < 2; ++it) {
            int slot = tid + it * 256;       // 0..511
            int row  = slot >> 2;            // 0..127
            int seg  = slot & 3;             // 0..3 (8 bf16 each)
            uint4 va = *(const uint4*)&A[(long)(m0 + row) * C_ + k0 + seg * 8];
            *(uint4*)&As[row * LDSTR + seg * 8] = va;
            uint4 vb = *(const uint4*)&Bt[(n0 + row) * C_ + k0 + seg * 8];
            *(uint4*)&Bs[row * LDSTR + seg * 8] = vb;
        }
        __syncthreads();

        bf16x8 af[4], bfr[4];
#pragma unroll
        for (int m = 0; m < 4; ++m)
            af[m] = *(const bf16x8*)&As[(wr * 64 + m * 16 + r16) * LDSTR + kg * 8];
#pragma unroll
        for (int n = 0; n < 4; ++n)
            bfr[n] = *(const bf16x8*)&Bs[(wc * 64 + n * 16 + r16) * LDSTR + kg * 8];

#pragma unroll
        for (int m = 0; m < 4; ++m)
#pragma unroll
            for (int n = 0; n < 4; ++n)
                acc[m][n] = __builtin_amdgcn_mfma_f32_16x16x32_bf16(af[m], bfr[n], acc[m][n], 0, 0, 0);
    }

    // epilogue: ReLU + fp32 store.  D layout: row=(l>>4)*4+r, col=l&15
    int rbase = m0 + wr * 64 + kg * 4;
    int cbase = n0 + wc * 64 + r16;
#pragma unroll
    for (int m = 0; m < 4; ++m)
#pragma unroll
        for (int n = 0; n < 4; ++n)
#pragma unroll
            for (int r = 0; r < 4; ++r) {
                float v = acc[m][n][r];
                v = v > 0.f ? v : 0.f;
                out[(long)(rbase + m * 16 + r) * F_ + cbase + n * 16] = v;
            }
}

extern "C" void kernel_launch(void* const* d_in, const int* in_sizes, int n_in,
                              void* d_out, int out_size, void* d_ws, size_t ws_size,
                              hipStream_t stream) {
    const float* x  = (const float*)d_in[0];
    const float* Wd = (const float*)d_in[1];
    const float* Wp = (const float*)d_in[2];
    float* out = (float*)d_out;

    bf16_t* dw  = (bf16_t*)d_ws;                                  // M_*C_ bf16 = 62,914,560 B
    bf16_t* WpT = (bf16_t*)((char*)d_ws + (size_t)M_ * C_ * 2);   // + 131,072 B

    wp_transpose_kernel<<<C_, F_, 0, stream>>>(Wp, WpT);
    dw_conv_kernel<<<(H_ / 8) * (W_ / 2), 256, 0, stream>>>(x, Wd, dw);
    gemm_kernel<<<dim3(M_ / BM, F_ / BN), 256, 0, stream>>>(dw, WpT, out);
}

// Round 18
// 102.763 us; speedup vs baseline: 1.2757x; 1.0193x over previous
//
#include <hip/hip_runtime.h>
#include <hip/hip_bf16.h>

#define T_ 8
#define H_ 96
#define W_ 160
#define C_ 256
#define F_ 256
#define M_ (T_ * H_ * W_)   // 122880

typedef __bf16 bf16_t;
typedef __bf16 bf16x8 __attribute__((ext_vector_type(8)));
typedef float  f32x4  __attribute__((ext_vector_type(4)));

// ---------------- pass 0: WpT[f][c] = bf16(Wp[c][f]) ----------------
__global__ void wp_transpose_kernel(const float* __restrict__ Wp,
                                    bf16_t* __restrict__ WpT) {
    int c = blockIdx.x;   // 0..255
    int f = threadIdx.x;  // 0..255
    WpT[f * C_ + c] = (bf16_t)Wp[c * F_ + f];
}

// ---------------- pass 1: depthwise 3x3x3, rolling 16-h strip, w-pair, scalar --
// Two-term law (fits r15/r17 exactly): dur = 0.0336*I[k-wave-instr]
//   + 0.0976*B[MB requested].  r17 (strip 8): I=1229k, B=315 -> 72us.
// Strip 16: h-amp 1.25->1.125, halo reloads drop -> I=1106k, B=284 -> ~65us.
// Live regs unchanged (window stays 3 h-sets): v 32 + acc 48 + wreg 27 ~ 122.
// 128-thr blocks (c-half) keep block-packing fine: grid 6x80x2 = 960.
#define PLANE(I)                                                              \
  {                                                                           \
    const int hh = h0 + (I) - 1;                                              \
    float v[4][8];                                                            \
    _Pragma("unroll") for (int j = 0; j < 4; ++j)                             \
      _Pragma("unroll") for (int tt = 0; tt < 8; ++tt) v[j][tt] = 0.f;        \
    if (hh >= 0 && hh < H_) {            /* block-uniform */                  \
      const float* pb = x + (((long)hh * W_ + w0) * C_ + c);                  \
      _Pragma("unroll") for (int tt = 0; tt < 8; ++tt)                        \
        v[1][tt] = pb[(long)tt * tstride];                                    \
      _Pragma("unroll") for (int tt = 0; tt < 8; ++tt)                        \
        v[2][tt] = pb[C_ + (long)tt * tstride];                               \
      if (hasL) {                                                             \
        _Pragma("unroll") for (int tt = 0; tt < 8; ++tt)                      \
          v[0][tt] = pb[-C_ + (long)tt * tstride];                            \
      }                                                                       \
      if (hasR) {                                                             \
        _Pragma("unroll") for (int tt = 0; tt < 8; ++tt)                      \
          v[3][tt] = pb[2 * C_ + (long)tt * tstride];                         \
      }                                                                       \
    }                                                                         \
    _Pragma("unroll") for (int kh = 0; kh < 3; ++kh) {                        \
      const int ko = (I) - kh;           /* literal after unroll */           \
      if (ko >= 0 && ko <= 15) {                                              \
        _Pragma("unroll") for (int to = 0; to < 8; ++to) {                    \
          float s0 = 0.f, s1 = 0.f;                                           \
          _Pragma("unroll") for (int kt = 0; kt < 3; ++kt) {                  \
            const int ti = to + kt - 1;                                       \
            if (ti >= 0 && ti < 8) {                                          \
              _Pragma("unroll") for (int kw = 0; kw < 3; ++kw) {              \
                const float wv = wreg[(kt * 3 + kh) * 3 + kw];                \
                s0 += v[kw][ti] * wv;                                         \
                s1 += v[kw + 1][ti] * wv;                                     \
              }                                                               \
            }                                                                 \
          }                                                                   \
          if (kh == 0) { acc[ko][to][0] = s0;  acc[ko][to][1] = s1; }         \
          else         { acc[ko][to][0] += s0; acc[ko][to][1] += s1; }        \
        }                                                                     \
      }                                                                       \
    }                                                                         \
    const int kd = (I) - 2;                                                   \
    if (kd >= 0 && kd <= 15) {                                                \
      _Pragma("unroll") for (int tt = 0; tt < 8; ++tt) {                      \
        bf16_t* pd = &dw[(((long)tt * H_ + h0 + kd) * W_ + w0) * C_ + c];     \
        pd[0]  = (bf16_t)acc[kd][tt][0];                                      \
        pd[C_] = (bf16_t)acc[kd][tt][1];                                      \
      }                                                                       \
    }                                                                         \
  }

__global__ __launch_bounds__(128, 2) void dw_conv_kernel(const float* __restrict__ x,
                                                         const float* __restrict__ Wd,
                                                         bf16_t* __restrict__ dw) {
    // XCD-chunked swizzle: grid 960 % 8 == 0 -> bijective
    int nchunk = gridDim.x >> 3;
    int bb  = (blockIdx.x & 7) * nchunk + (blockIdx.x >> 3);
    // c-half innermost: spatially adjacent blocks stay adjacent for L2 halos
    int ch  = bb & 1;
    int sp  = bb >> 1;               // 0..479
    int hs  = sp / (W_ / 2);         // strip, 0..5
    int wp  = sp % (W_ / 2);         // w-pair, 0..79
    int h0  = hs * 16;
    int w0  = wp * 2;                // outputs {w0, w0+1}
    int c   = ch * 128 + threadIdx.x;

    const bool hasL = (w0 > 0);          // block-uniform
    const bool hasR = (w0 + 2 < W_);     // block-uniform
    const int tstride = H_ * W_ * C_;

    float wreg[27];
#pragma unroll
    for (int k = 0; k < 27; ++k) wreg[k] = Wd[k * C_ + c];

    float acc[16][8][2];             // [h-out][t][iw]; live window <= 3 h-sets

    PLANE(0)  PLANE(1)  PLANE(2)  PLANE(3)  PLANE(4)  PLANE(5)
    PLANE(6)  PLANE(7)  PLANE(8)  PLANE(9)  PLANE(10) PLANE(11)
    PLANE(12) PLANE(13) PLANE(14) PLANE(15) PLANE(16) PLANE(17)
}

// ---------------- pass 2: GEMM [M,256]x[256,256] bf16 MFMA + ReLU ----------------
#define BM 128
#define BN 128
#define BK 32
#define LDSTR 40  // 32 + 8 pad: fragment ds_read_b128 2-way (free) instead of 8-way

__global__ __launch_bounds__(256) void gemm_kernel(const bf16_t* __restrict__ A,   // dw  [M][C]
                                                   const bf16_t* __restrict__ Bt,  // WpT [F][C] (n-major)
                                                   float* __restrict__ out) {      // [M][F]
    __shared__ __align__(16) bf16_t As[BM * LDSTR];
    __shared__ __align__(16) bf16_t Bs[BN * LDSTR];

    int m0   = blockIdx.x * BM;
    int n0   = blockIdx.y * BN;
    int tid  = threadIdx.x;
    int lane = tid & 63;
    int wid  = tid >> 6;
    int wr   = wid >> 1;   // 0..1
    int wc   = wid & 1;    // 0..1
    int r16  = lane & 15;
    int kg   = lane >> 4;  // 0..3

    f32x4 acc[4][4] = {};

    for (int k0 = 0; k0 < C_; k0 += BK) {
        __syncthreads();
#pragma unroll
        for (int it = 0; it < 2; ++it) {
            int slot = tid + it * 256;       // 0..511
            int row  = slot >> 2;            // 0..127
            int seg  = slot & 3;             // 0..3 (8 bf16 each)
            uint4 va = *(const uint4*)&A[(long)(m0 + row) * C_ + k0 + seg * 8];
            *(uint4*)&As[row * LDSTR + seg * 8] = va;
            uint4 vb = *(const uint4*)&Bt[(n0 + row) * C_ + k0 + seg * 8];
            *(uint4*)&Bs[row * LDSTR + seg * 8] = vb;
        }
        __syncthreads();

        bf16x8 af[4], bfr[4];
#pragma unroll
        for (int m = 0; m < 4; ++m)
            af[m] = *(const bf16x8*)&As[(wr * 64 + m * 16 + r16) * LDSTR + kg * 8];
#pragma unroll
        for (int n = 0; n < 4; ++n)
            bfr[n] = *(const bf16x8*)&Bs[(wc * 64 + n * 16 + r16) * LDSTR + kg * 8];

#pragma unroll
        for (int m = 0; m < 4; ++m)
#pragma unroll
            for (int n = 0; n < 4; ++n)
                acc[m][n] = __builtin_amdgcn_mfma_f32_16x16x32_bf16(af[m], bfr[n], acc[m][n], 0, 0, 0);
    }

    // epilogue: ReLU + fp32 store.  D layout: row=(l>>4)*4+r, col=l&15
    int rbase = m0 + wr * 64 + kg * 4;
    int cbase = n0 + wc * 64 + r16;
#pragma unroll
    for (int m = 0; m < 4; ++m)
#pragma unroll
        for (int n = 0; n < 4; ++n)
#pragma unroll
            for (int r = 0; r < 4; ++r) {
                float v = acc[m][n][r];
                v = v > 0.f ? v : 0.f;
                out[(long)(rbase + m * 16 + r) * F_ + cbase + n * 16] = v;
            }
}

extern "C" void kernel_launch(void* const* d_in, const int* in_sizes, int n_in,
                              void* d_out, int out_size, void* d_ws, size_t ws_size,
                              hipStream_t stream) {
    const float* x  = (const float*)d_in[0];
    const float* Wd = (const float*)d_in[1];
    const float* Wp = (const float*)d_in[2];
    float* out = (float*)d_out;

    bf16_t* dw  = (bf16_t*)d_ws;                                  // M_*C_ bf16 = 62,914,560 B
    bf16_t* WpT = (bf16_t*)((char*)d_ws + (size_t)M_ * C_ * 2);   // + 131,072 B

    wp_transpose_kernel<<<C_, F_, 0, stream>>>(Wp, WpT);
    dw_conv_kernel<<<(H_ / 16) * (W_ / 2) * 2, 128, 0, stream>>>(x, Wd, dw);
    gemm_kernel<<<dim3(M_ / BM, F_ / BN), 256, 0, stream>>>(dw, WpT, out);
}

// Round 19
// 99.164 us; speedup vs baseline: 1.3220x; 1.0363x over previous
//
#include <hip/hip_runtime.h>
#include <hip/hip_bf16.h>

#define T_ 8
#define H_ 96
#define W_ 160
#define C_ 256
#define F_ 256
#define M_ (T_ * H_ * W_)   // 122880

typedef __bf16 bf16_t;
typedef __bf16 bf16x8 __attribute__((ext_vector_type(8)));
typedef float  f32x4  __attribute__((ext_vector_type(4)));

// ---------------- pass 0: WpT[f][c] = bf16(Wp[c][f]) ----------------
__global__ void wp_transpose_kernel(const float* __restrict__ Wp,
                                    bf16_t* __restrict__ WpT) {
    int c = blockIdx.x;   // 0..255
    int f = threadIdx.x;  // 0..255
    WpT[f * C_ + c] = (bf16_t)Wp[c * F_ + f];
}

// ---------------- pass 1: depthwise 3x3x3, rolling 12-h strip, w-pair, scalar --
// Two-term law: dur = 0.0336*I[k-wave-instr] + 0.0976*B[MB requested], with
// coefficient degradation below ~10 waves/CU. r17 (strip8, 15w/CU)=72;
// r18 (strip16, 7.5w/CU)=70.7. Strip-12 balances: grid 1280 -> 10 w/CU,
// I=1147k, B=294MB -> ~67us. Window-3 regs unchanged (VGPR ~84).
#define PLANE(I)                                                              \
  {                                                                           \
    const int hh = h0 + (I) - 1;                                              \
    float v[4][8];                                                            \
    _Pragma("unroll") for (int j = 0; j < 4; ++j)                             \
      _Pragma("unroll") for (int tt = 0; tt < 8; ++tt) v[j][tt] = 0.f;        \
    if (hh >= 0 && hh < H_) {            /* block-uniform */                  \
      const float* pb = x + (((long)hh * W_ + w0) * C_ + c);                  \
      _Pragma("unroll") for (int tt = 0; tt < 8; ++tt)                        \
        v[1][tt] = pb[(long)tt * tstride];                                    \
      _Pragma("unroll") for (int tt = 0; tt < 8; ++tt)                        \
        v[2][tt] = pb[C_ + (long)tt * tstride];                               \
      if (hasL) {                                                             \
        _Pragma("unroll") for (int tt = 0; tt < 8; ++tt)                      \
          v[0][tt] = pb[-C_ + (long)tt * tstride];                            \
      }                                                                       \
      if (hasR) {                                                             \
        _Pragma("unroll") for (int tt = 0; tt < 8; ++tt)                      \
          v[3][tt] = pb[2 * C_ + (long)tt * tstride];                         \
      }                                                                       \
    }                                                                         \
    _Pragma("unroll") for (int kh = 0; kh < 3; ++kh) {                        \
      const int ko = (I) - kh;           /* literal after unroll */           \
      if (ko >= 0 && ko <= 11) {                                              \
        _Pragma("unroll") for (int to = 0; to < 8; ++to) {                    \
          float s0 = 0.f, s1 = 0.f;                                           \
          _Pragma("unroll") for (int kt = 0; kt < 3; ++kt) {                  \
            const int ti = to + kt - 1;                                       \
            if (ti >= 0 && ti < 8) {                                          \
              _Pragma("unroll") for (int kw = 0; kw < 3; ++kw) {              \
                const float wv = wreg[(kt * 3 + kh) * 3 + kw];                \
                s0 += v[kw][ti] * wv;                                         \
                s1 += v[kw + 1][ti] * wv;                                     \
              }                                                               \
            }                                                                 \
          }                                                                   \
          if (kh == 0) { acc[ko][to][0] = s0;  acc[ko][to][1] = s1; }         \
          else         { acc[ko][to][0] += s0; acc[ko][to][1] += s1; }        \
        }                                                                     \
      }                                                                       \
    }                                                                         \
    const int kd = (I) - 2;                                                   \
    if (kd >= 0 && kd <= 11) {                                                \
      _Pragma("unroll") for (int tt = 0; tt < 8; ++tt) {                      \
        bf16_t* pd = &dw[(((long)tt * H_ + h0 + kd) * W_ + w0) * C_ + c];     \
        pd[0]  = (bf16_t)acc[kd][tt][0];                                      \
        pd[C_] = (bf16_t)acc[kd][tt][1];                                      \
      }                                                                       \
    }                                                                         \
  }

__global__ __launch_bounds__(128, 2) void dw_conv_kernel(const float* __restrict__ x,
                                                         const float* __restrict__ Wd,
                                                         bf16_t* __restrict__ dw) {
    // XCD-chunked swizzle: grid 1280 % 8 == 0 -> bijective
    int nchunk = gridDim.x >> 3;
    int bb  = (blockIdx.x & 7) * nchunk + (blockIdx.x >> 3);
    // c-half innermost: spatially adjacent blocks stay adjacent for L2 halos
    int ch  = bb & 1;
    int sp  = bb >> 1;               // 0..639
    int hs  = sp / (W_ / 2);         // strip, 0..7
    int wp  = sp % (W_ / 2);         // w-pair, 0..79
    int h0  = hs * 12;
    int w0  = wp * 2;                // outputs {w0, w0+1}
    int c   = ch * 128 + threadIdx.x;

    const bool hasL = (w0 > 0);          // block-uniform
    const bool hasR = (w0 + 2 < W_);     // block-uniform
    const int tstride = H_ * W_ * C_;

    float wreg[27];
#pragma unroll
    for (int k = 0; k < 27; ++k) wreg[k] = Wd[k * C_ + c];

    float acc[12][8][2];             // [h-out][t][iw]; live window <= 3 h-sets

    PLANE(0)  PLANE(1)  PLANE(2)  PLANE(3)  PLANE(4)  PLANE(5)  PLANE(6)
    PLANE(7)  PLANE(8)  PLANE(9)  PLANE(10) PLANE(11) PLANE(12) PLANE(13)
}

// ---------------- pass 2: GEMM [M,256]x[256,256] bf16 MFMA + ReLU ----------------
// BN=256 (full F per block) kills the 2x A-re-read: requests 378 -> 315 MB.
// 512 threads, 8 waves = 2(m) x 4(f); per-wave shape identical to the proven
// 64x64 kernel (4 A-frags x 4 B-frags), only staging/indexing relabeled.
#define BM 128
#define BN 256
#define BK 32
#define LDSTR 40  // 32 + 8 pad: fragment ds_read_b128 2-way (free) instead of 8-way

__global__ __launch_bounds__(512) void gemm_kernel(const bf16_t* __restrict__ A,   // dw  [M][C]
                                                   const bf16_t* __restrict__ Bt,  // WpT [F][C] (n-major)
                                                   float* __restrict__ out) {      // [M][F]
    __shared__ __align__(16) bf16_t As[BM * LDSTR];
    __shared__ __align__(16) bf16_t Bs[BN * LDSTR];

    int m0   = blockIdx.x * BM;
    int tid  = threadIdx.x;
    int lane = tid & 63;
    int wid  = tid >> 6;   // 0..7
    int wr   = wid >> 2;   // 0..1  (m-half)
    int wc   = wid & 3;    // 0..3  (f-quarter)
    int r16  = lane & 15;
    int kg   = lane >> 4;  // 0..3

    f32x4 acc[4][4] = {};

    for (int k0 = 0; k0 < C_; k0 += BK) {
        __syncthreads();
        // stage A tile [128 x 32]: 512 slots, 1 per thread
        {
            int row = tid >> 2, seg = tid & 3;
            uint4 va = *(const uint4*)&A[(long)(m0 + row) * C_ + k0 + seg * 8];
            *(uint4*)&As[row * LDSTR + seg * 8] = va;
        }
        // stage B tile [256 x 32]: 1024 slots, 2 per thread
#pragma unroll
        for (int it = 0; it < 2; ++it) {
            int slot = tid + it * 512;
            int row  = slot >> 2, seg = slot & 3;
            uint4 vb = *(const uint4*)&Bt[(long)row * C_ + k0 + seg * 8];
            *(uint4*)&Bs[row * LDSTR + seg * 8] = vb;
        }
        __syncthreads();

        bf16x8 af[4], bfr[4];
#pragma unroll
        for (int m = 0; m < 4; ++m)
            af[m] = *(const bf16x8*)&As[(wr * 64 + m * 16 + r16) * LDSTR + kg * 8];
#pragma unroll
        for (int n = 0; n < 4; ++n)
            bfr[n] = *(const bf16x8*)&Bs[(wc * 64 + n * 16 + r16) * LDSTR + kg * 8];

#pragma unroll
        for (int m = 0; m < 4; ++m)
#pragma unroll
            for (int n = 0; n < 4; ++n)
                acc[m][n] = __builtin_amdgcn_mfma_f32_16x16x32_bf16(af[m], bfr[n], acc[m][n], 0, 0, 0);
    }

    // epilogue: ReLU + fp32 store.  D layout: row=(l>>4)*4+r, col=l&15
    int rbase = m0 + wr * 64 + kg * 4;
    int cbase = wc * 64 + r16;
#pragma unroll
    for (int m = 0; m < 4; ++m)
#pragma unroll
        for (int n = 0; n < 4; ++n)
#pragma unroll
            for (int r = 0; r < 4; ++r) {
                float v = acc[m][n][r];
                v = v > 0.f ? v : 0.f;
                out[(long)(rbase + m * 16 + r) * F_ + cbase + n * 16] = v;
            }
}

extern "C" void kernel_launch(void* const* d_in, const int* in_sizes, int n_in,
                              void* d_out, int out_size, void* d_ws, size_t ws_size,
                              hipStream_t stream) {
    const float* x  = (const float*)d_in[0];
    const float* Wd = (const float*)d_in[1];
    const float* Wp = (const float*)d_in[2];
    float* out = (float*)d_out;

    bf16_t* dw  = (bf16_t*)d_ws;                                  // M_*C_ bf16 = 62,914,560 B
    bf16_t* WpT = (bf16_t*)((char*)d_ws + (size_t)M_ * C_ * 2);   // + 131,072 B

    wp_transpose_kernel<<<C_, F_, 0, stream>>>(Wp, WpT);
    dw_conv_kernel<<<(H_ / 12) * (W_ / 2) * 2, 128, 0, stream>>>(x, Wd, dw);
    gemm_kernel<<<M_ / BM, 512, 0, stream>>>(dw, WpT, out);
}